// Round 9
// baseline (10232.776 us; speedup 1.0000x reference)
//
#include <hip/hip_runtime.h>

// ============================================================================
// Neural CDE forward, MI355X. B=256, L=1024, I=16, H=128, W=512, O=4.
//
// 16 clusters x 16 blocks (256 = #CUs, co-resident). Cluster owns 16 batch
// rows. Weights resident in VGPRs (Wf1 replicated, Wf2 col-sliced, Wf3
// K-sliced). y state: full 16x128 fp32 replicated in every block.
//
// NUMERICS (new): all activations feeding MFMAs are hi/lo bf16 pairs
// (y, h1, h2*dx products; h2 kept fp32 in LDS) -> quantization noise
// 2^-9 -> ~2^-17. The ODE amplifies per-step rounding noise ~10^3-5x over
// 1023 steps (rounds 1-6 straddled the threshold at 2^-8..2^-6); this cuts
// the noise floor decisively. Weights stay single bf16 (systematic part,
// present in every passing round).
//
// EXCHANGE (1 RTT): each block scatters its fp32 partial dy (16x128) to its
// own slot (relaxed agent stores), drains, bumps a per-parity counter (RMW);
// consumers poll the counter, then all-read the 16 slots and reduce locally.
// 2-parity rotation; overwrite race-free via the bump<=read dependence chain.
// ============================================================================

constexpr int LQ = 1024, IQ = 16, HQ = 128, WQ = 512, OQ = 4;
constexpr int THREADS = 512;
constexpr size_t PCS   = 270336;
constexpr size_t PBASE = 65536;

typedef __attribute__((ext_vector_type(8))) short bf16x8;
typedef __attribute__((ext_vector_type(4))) float f32x4;
typedef unsigned int u32t;
typedef unsigned long long u64t;

#define MFMA16(a, b, c) __builtin_amdgcn_mfma_f32_16x16x32_bf16((a), (b), (c), 0, 0, 0)

__device__ __forceinline__ unsigned short f2bf(float f) {
  unsigned u = __builtin_bit_cast(unsigned, f);
  u += 0x7FFFu + ((u >> 16) & 1u);  // RNE
  return (unsigned short)(u >> 16);
}
__device__ __forceinline__ float bf2f(unsigned short h) {
  unsigned u = ((unsigned)h) << 16;
  return __builtin_bit_cast(float, u);
}
__device__ __forceinline__ float fast_tanh(float x) {
  float e = __expf(2.0f * x);
  return 1.0f - 2.0f / (e + 1.0f);
}
__device__ __forceinline__ u32t cvtpk(float lo, float hi) {
  u32t r;
  asm("v_cvt_pk_bf16_f32 %0, %1, %2" : "=v"(r) : "v"(lo), "v"(hi));
  return r;
}
// residual pair: given p0,p1 and their packed bf16 hi word, pack (p-hi) to bf16
__device__ __forceinline__ u32t lo_pair(float p0, float p1, u32t hpk) {
  float h0 = __builtin_bit_cast(float, hpk << 16);
  float h1 = __builtin_bit_cast(float, hpk & 0xffff0000u);
  return cvtpk(p0 - h0, p1 - h1);
}

// B-fragment: lane holds B[k0+8*(lane>>4)+j][n0+(lane&15)]
__device__ __forceinline__ bf16x8 load_bfrag(const float* W, int N, int k0, int n0, int lane) {
  const int col = n0 + (lane & 15);
  const int kb  = k0 + 8 * (lane >> 4);
  bf16x8 v;
#pragma unroll
  for (int j = 0; j < 8; ++j) v[j] = (short)f2bf(W[(kb + j) * N + col]);
  return v;
}

// ---- proven comm primitives: relaxed agent-scope atomics ----
__device__ __forceinline__ void st32a(u32t* p, u32t v) {
  __hip_atomic_store(p, v, __ATOMIC_RELAXED, __HIP_MEMORY_SCOPE_AGENT);
}
__device__ __forceinline__ u32t ld32a(const u32t* p) {
  return __hip_atomic_load(p, __ATOMIC_RELAXED, __HIP_MEMORY_SCOPE_AGENT);
}
__device__ __forceinline__ u64t ld64a(const u64t* p) {
  return __hip_atomic_load(p, __ATOMIC_RELAXED, __HIP_MEMORY_SCOPE_AGENT);
}
__device__ __forceinline__ void pollge(const u32t* p, u32t want) {
  while (ld32a(p) < want) __builtin_amdgcn_s_sleep(1);
  asm volatile("" ::: "memory");
}
__device__ __forceinline__ void drain_all() { __builtin_amdgcn_s_waitcnt(0); }

// ---- LDS pool layout (63.0 KB < 64 KB) ----
constexpr int OFF_YSH = 0;       // u16 y_sh[16][136]   4352            (epi: gep)
constexpr int OFF_YSL = 4352;    // u16 y_sl[16][136]   4352  -> 8704
constexpr int OFF_H1H = 8704;    // u16 h1h[16][520]   16640  -> 25344
constexpr int OFF_H1L = 25344;   // u16 h1l[16][520]   16640  -> 41984
constexpr int OFF_RED = 41984;   // f32 red[8][16][33] 16896  -> 58880  (epi: yf)
constexpr int OFF_B1  = 58880;   // f32 b1s[512]        2048  -> 60928
constexpr int OFF_B2  = 60928;   // f32 b2s[32]          128  -> 61056
constexpr int OFF_H2F = 61056;   // f32 h2f[16][33]     2112  -> 63168
constexpr int OFF_DX  = 63168;   // f32 dxs[16][20]     1280  -> 64448
constexpr int OFF_DT  = 64448;   // f32 dtl[16]           64  -> 64512
constexpr int POOLSZ  = 64512;
// h0f f32[16][512] (init only) overlays [0, 32768).

// ---- ws layout ----
// ws + c*256 + par*128          : u32 cnt[2]
// ws + 8192 + c*64              : u32 fy[16] (init broadcast flags)
// ws + PBASE + c*PCS            : f32 partial[par*16 + r][16*128]  (256 KB)
// ws + PBASE + c*PCS + 262144   : f32 y0b[16*128]                  (8 KB)

__global__ __launch_bounds__(THREADS, 1) void cde_kernel(
    const float* __restrict__ ts,  const float* __restrict__ x,
    const float* __restrict__ Wi1, const float* __restrict__ bi1,
    const float* __restrict__ Wi2, const float* __restrict__ bi2,
    const float* __restrict__ Wf1, const float* __restrict__ bfv1,
    const float* __restrict__ Wf2, const float* __restrict__ bfv2,
    const float* __restrict__ Wf3, const float* __restrict__ bfv3,
    const float* __restrict__ Wo1, const float* __restrict__ bo1,
    const float* __restrict__ Wo2, const float* __restrict__ bo2,
    float* __restrict__ out, unsigned char* __restrict__ ws) {
  const int tid  = threadIdx.x;
  const int wave = tid >> 6;
  const int lane = tid & 63;
  const int bid  = blockIdx.x;
  const int c    = bid >> 4;   // cluster: batch rows [16c, 16c+16)
  const int r    = bid & 15;   // rank: Wf2 cols [32r..), Wf3 rows [32r..)

  u32t* cnt = (u32t*)(ws + (size_t)c * 256);
  u32t* fy  = (u32t*)(ws + 8192 + (size_t)c * 64);
  float* part = (float*)(ws + PBASE + (size_t)c * PCS);
  float* y0b  = (float*)(ws + PBASE + (size_t)c * PCS + 262144);

  __shared__ __align__(16) unsigned char pool[POOLSZ];
  auto y_sh = (unsigned short(*)[136])(pool + OFF_YSH);
  auto y_sl = (unsigned short(*)[136])(pool + OFF_YSL);
  auto h1h  = (unsigned short(*)[520])(pool + OFF_H1H);
  auto h1l  = (unsigned short(*)[520])(pool + OFF_H1L);
  auto red  = (float(*)[16][33])(pool + OFF_RED);
  auto h2f  = (float(*)[33])(pool + OFF_H2F);
  auto h0f  = (float(*)[512])(pool);                 // init only
  float* b1s = (float*)(pool + OFF_B1);
  float* b2s = (float*)(pool + OFF_B2);
  float* dxs = (float*)(pool + OFF_DX);
  float* dtl = (float*)(pool + OFF_DT);

  // ---- resident weight fragments (single bf16, as all passing rounds) ----
  bf16x8 w1f[4][4];   // Wf1 replicated: wave w -> h1 cols [64w, 64w+64)
#pragma unroll
  for (int n = 0; n < 4; ++n)
#pragma unroll
    for (int k4 = 0; k4 < 4; ++k4)
      w1f[n][k4] = load_bfrag(Wf1, WQ, 32 * k4, 64 * wave + 16 * n, lane);
  const int w_nt = wave & 1, w_q = wave >> 1;
  bf16x8 w2f[4];      // Wf2 slice: n-half w_nt of cols [32r,32r+32), K-quarter w_q
#pragma unroll
  for (int kk = 0; kk < 4; ++kk)
    w2f[kk] = load_bfrag(Wf2, WQ, 32 * (4 * w_q + kk), 32 * r + 16 * w_nt, lane);
  bf16x8 w3f[16];     // B'[(k,j)][h] = Wf3[32r+k][16h+j]; wave -> h [16w,16w+16)
  {
    const int h = 16 * wave + (lane & 15);
#pragma unroll
    for (int kk = 0; kk < 16; ++kk) {
      bf16x8 v;
#pragma unroll
      for (int jj = 0; jj < 8; ++jj) {
        int Kp = 32 * kk + 8 * (lane >> 4) + jj;
        int k = Kp >> 4, j = Kp & 15;
        v[jj] = (short)f2bf(Wf3[(32 * r + k) * (HQ * IQ) + 16 * h + j]);
      }
      w3f[kk] = v;
    }
  }
  bf16x8 w3b;         // bias frag: B''[Kpp][h] = (Kpp<16) ? bfv3[16h+Kpp] : 0
  {
    const int h = 16 * wave + (lane & 15);
    bf16x8 v;
#pragma unroll
    for (int jj = 0; jj < 8; ++jj) {
      int Kpp = 8 * (lane >> 4) + jj;
      v[jj] = (Kpp < 16) ? (short)f2bf(bfv3[16 * h + Kpp]) : (short)0;
    }
    w3b = v;
  }

  b1s[tid] = bi1[tid];
  if (tid < 32) b2s[tid] = bfv2[32 * r + tid];

  // ---- init: h0 = tanh(x0 @ Wi1 + bi1); y0 slice = h0 @ Wi2 + bi2 ----
  {
    int row = tid >> 5, col0 = (tid & 31) * 16;
    const float* xr = x + ((16 * c + row) * LQ) * IQ;
    float xv[16];
#pragma unroll
    for (int j = 0; j < 16; ++j) xv[j] = xr[j];
    for (int cc = 0; cc < 16; ++cc) {
      int col = col0 + cc;
      float s = bi1[col];
#pragma unroll
      for (int j = 0; j < 16; ++j) s += xv[j] * Wi1[j * WQ + col];
      h0f[row][col] = tanhf(s);
    }
  }
  __syncthreads();
  if (tid < 128) {      // publish y0 slice (fp32) cols [8r, 8r+8)
    int m = tid >> 3, hl = tid & 7;
    float s = bi2[8 * r + hl];
#pragma unroll 8
    for (int k = 0; k < WQ; ++k) s += h0f[m][k] * Wi2[k * HQ + 8 * r + hl];
    st32a((u32t*)&y0b[m * HQ + 8 * r + hl], __builtin_bit_cast(u32t, s));
  }
  drain_all();
  __syncthreads();      // h0f reads done -> pool reusable
  if (tid == 0) st32a(fy + r, 1u);
  f32x4 y4;             // thread owns y[tid>>5][4*(tid&31) .. +4) fp32
  {
    pollge(fy + ((tid & 31) >> 1), 1u);
    u64t a = ld64a((const u64t*)(y0b + tid * 4));
    u64t b = ld64a((const u64t*)(y0b + tid * 4 + 2));
    y4[0] = __builtin_bit_cast(float, (u32t)a);
    y4[1] = __builtin_bit_cast(float, (u32t)(a >> 32));
    y4[2] = __builtin_bit_cast(float, (u32t)b);
    y4[3] = __builtin_bit_cast(float, (u32t)(b >> 32));
  }
  __syncthreads();

  const int g_row = tid >> 5, g_c4 = 4 * (tid & 31);
  const float* xrow = x + ((size_t)(16 * c + (tid >> 4))) * LQ * IQ + (tid & 15);
  const float* tsp  = ts + (size_t)(16 * c + tid) * LQ;

  // ======================= main scan: 1023 steps =======================
  for (int t = 0; t < LQ - 1; ++t) {
    const int par = t & 1;
    u32t* cntP = cnt + par * 32;
    float* slotW = part + (size_t)(par * 16 + r) * 2048;

    // issue dx/dt loads early
    float xa = 0.f, xb = 0.f, ta = 0.f, tb = 0.f;
    if (tid < 256) { const float* xp = xrow + t * IQ; xa = xp[0]; xb = xp[IQ]; }
    if (tid < 16)  { ta = tsp[t]; tb = tsp[t + 1]; }
    // pack y hi/lo (fp32 regs -> bf16 pair in LDS)
    {
      u32t h0 = cvtpk(y4[0], y4[1]), h1 = cvtpk(y4[2], y4[3]);
      u32t g0 = lo_pair(y4[0], y4[1], h0), g1 = lo_pair(y4[2], y4[3], h1);
      *(u64t*)&y_sh[g_row][g_c4] = ((u64t)h1 << 32) | (u64t)h0;
      *(u64t*)&y_sl[g_row][g_c4] = ((u64t)g1 << 32) | (u64t)g0;
    }
    __syncthreads();                                       // B1
    if (tid < 256) dxs[(tid >> 4) * 20 + (tid & 15)] = xb - xa;
    if (tid < 16)  dtl[tid] = tb - ta;
    // ---- P1: h1 = tanh((yh+yl) @ Wf1 + b1), wave w -> cols [64w, 64w+64) ----
    {
      bf16x8 afh[4], afl[4];
#pragma unroll
      for (int k4 = 0; k4 < 4; ++k4) {
        afh[k4] = *(const bf16x8*)&y_sh[lane & 15][32 * k4 + 8 * (lane >> 4)];
        afl[k4] = *(const bf16x8*)&y_sl[lane & 15][32 * k4 + 8 * (lane >> 4)];
      }
#pragma unroll
      for (int n = 0; n < 4; ++n) {
        f32x4 acc = {0.f, 0.f, 0.f, 0.f};
#pragma unroll
        for (int k4 = 0; k4 < 4; ++k4) acc = MFMA16(afh[k4], w1f[n][k4], acc);
#pragma unroll
        for (int k4 = 0; k4 < 4; ++k4) acc = MFMA16(afl[k4], w1f[n][k4], acc);
        const int col = 64 * wave + 16 * n + (lane & 15);
        const float bb = b1s[col];
#pragma unroll
        for (int i = 0; i < 4; ++i) {
          float hv = fast_tanh(acc[i] + bb);
          unsigned short hh = f2bf(hv);
          h1h[4 * (lane >> 4) + i][col] = hh;
          h1l[4 * (lane >> 4) + i][col] = f2bf(hv - bf2f(hh));
        }
      }
    }
    __syncthreads();                                       // B2
    // ---- P2: h2 slice partials, (h1h+h1l) @ Wf2 ----
    {
      f32x4 a0 = {0.f, 0.f, 0.f, 0.f}, a1 = {0.f, 0.f, 0.f, 0.f};
#pragma unroll
      for (int kk = 0; kk < 2; ++kk) {
        const int o0 = 32 * (4 * w_q + kk) + 8 * (lane >> 4);
        const int o1 = 32 * (4 * w_q + kk + 2) + 8 * (lane >> 4);
        a0 = MFMA16(*(const bf16x8*)&h1h[lane & 15][o0], w2f[kk], a0);
        a0 = MFMA16(*(const bf16x8*)&h1l[lane & 15][o0], w2f[kk], a0);
        a1 = MFMA16(*(const bf16x8*)&h1h[lane & 15][o1], w2f[kk + 2], a1);
        a1 = MFMA16(*(const bf16x8*)&h1l[lane & 15][o1], w2f[kk + 2], a1);
      }
#pragma unroll
      for (int i = 0; i < 4; ++i)
        red[wave][4 * (lane >> 4) + i][lane & 15] = a0[i] + a1[i];
    }
    __syncthreads();                                       // B3
    if (tid < 256) {   // reduce 4 K-partials + bias + tanh -> h2f (fp32, LDS)
      int row = tid >> 4, cp = tid & 15;
      int c0 = 2 * cp, c1 = c0 + 1, nt = cp >> 3, l0 = c0 & 15, l1 = c1 & 15;
      float v0 = b2s[c0], v1 = b2s[c1];
#pragma unroll
      for (int q = 0; q < 4; ++q) {
        v0 += red[(q << 1) | nt][row][l0];
        v1 += red[(q << 1) | nt][row][l1];
      }
      h2f[row][c0] = fast_tanh(v0);
      h2f[row][c1] = fast_tanh(v1);
    }
    __syncthreads();                                       // B4
    // ---- P3: partial dy via K'=(k,j)=512 MFMA, A' split hi/lo ----
    {
      const int b = lane & 15;
      const int ksel = (lane >> 5) & 1;      // which k of the pair this lane handles
      float dxsel[8];
#pragma unroll
      for (int jj = 0; jj < 8; ++jj)
        dxsel[jj] = dxs[b * 20 + ((lane & 16) ? 8 : 0) + jj];
      float hvv[16];
#pragma unroll
      for (int kk = 0; kk < 16; ++kk) hvv[kk] = h2f[b][2 * kk + ksel];
      f32x4 acc = {0.f, 0.f, 0.f, 0.f};
#pragma unroll
      for (int kk = 0; kk < 16; ++kk) {
        const float hv = hvv[kk];
        float p0 = hv * dxsel[0], p1 = hv * dxsel[1], p2 = hv * dxsel[2], p3 = hv * dxsel[3];
        float p4 = hv * dxsel[4], p5 = hv * dxsel[5], p6 = hv * dxsel[6], p7 = hv * dxsel[7];
        int4 hi, lo;
        hi.x = (int)cvtpk(p0, p1); lo.x = (int)lo_pair(p0, p1, (u32t)hi.x);
        hi.y = (int)cvtpk(p2, p3); lo.y = (int)lo_pair(p2, p3, (u32t)hi.y);
        hi.z = (int)cvtpk(p4, p5); lo.z = (int)lo_pair(p4, p5, (u32t)hi.z);
        hi.w = (int)cvtpk(p6, p7); lo.w = (int)lo_pair(p6, p7, (u32t)hi.w);
        acc = MFMA16(__builtin_bit_cast(bf16x8, hi), w3f[kk], acc);
        acc = MFMA16(__builtin_bit_cast(bf16x8, lo), w3f[kk], acc);
      }
      if (r == 0) {   // bias contribution (A'' = dx hi/lo), once per cluster
        int4 bh, bl;
        if (lane & 32) {
          bh.x = bh.y = bh.z = bh.w = 0; bl = bh;
        } else {
          bh.x = (int)cvtpk(dxsel[0], dxsel[1]); bl.x = (int)lo_pair(dxsel[0], dxsel[1], (u32t)bh.x);
          bh.y = (int)cvtpk(dxsel[2], dxsel[3]); bl.y = (int)lo_pair(dxsel[2], dxsel[3], (u32t)bh.y);
          bh.z = (int)cvtpk(dxsel[4], dxsel[5]); bl.z = (int)lo_pair(dxsel[4], dxsel[5], (u32t)bh.z);
          bh.w = (int)cvtpk(dxsel[6], dxsel[7]); bl.w = (int)lo_pair(dxsel[6], dxsel[7], (u32t)bh.w);
        }
        acc = MFMA16(__builtin_bit_cast(bf16x8, bh), w3b, acc);
        acc = MFMA16(__builtin_bit_cast(bf16x8, bl), w3b, acc);
      }
      // scatter fp32 partial to own slot
      const int hcol = 16 * wave + b;
#pragma unroll
      for (int i = 0; i < 4; ++i)
        st32a((u32t*)&slotW[(4 * (lane >> 4) + i) * 128 + hcol],
              __builtin_bit_cast(u32t, acc[i]));
    }
    drain_all();
    __syncthreads();                                       // B5
    if (tid == 0)
      __hip_atomic_fetch_add(cntP, 1u, __ATOMIC_RELAXED, __HIP_MEMORY_SCOPE_AGENT);
    pollge(cntP, 16u * (u32t)((t >> 1) + 1));
    // all-read the 16 partial slots (own 4 floats each), reduce, update y
    {
      float s0 = 0.f, s1 = 0.f, s2 = 0.f, s3 = 0.f;
#pragma unroll
      for (int i = 0; i < 16; ++i) {
        int rr = (r + i) & 15;   // stagger slot order across blocks
        const float* pb = part + (size_t)(par * 16 + rr) * 2048 + g_row * 128 + g_c4;
        u64t a = ld64a((const u64t*)pb);
        u64t b = ld64a((const u64t*)(pb + 2));
        s0 += __builtin_bit_cast(float, (u32t)a);
        s1 += __builtin_bit_cast(float, (u32t)(a >> 32));
        s2 += __builtin_bit_cast(float, (u32t)b);
        s3 += __builtin_bit_cast(float, (u32t)(b >> 32));
      }
      const float dtv = dtl[g_row];
      y4[0] += s0 * dtv; y4[1] += s1 * dtv; y4[2] += s2 * dtv; y4[3] += s3 * dtv;
    }
  }

  // ---- epilogue: y replicated fp32 in registers; block r==0 finishes ----
  if (r == 0) {
    float* yf = (float*)(pool + OFF_RED);   // f32 [16][128]
    {
#pragma unroll
      for (int i = 0; i < 4; ++i) yf[g_row * HQ + g_c4 + i] = y4[i];
    }
    __syncthreads();
    float* gep = (float*)(pool + OFF_YSH);  // f32 [16][32]
    {
      int m = tid >> 5, o = tid & 31;
      float s = bo1[o];
#pragma unroll 8
      for (int k = 0; k < HQ; ++k) s += yf[m * HQ + k] * Wo1[k * 32 + o];
      gep[m * 32 + o] = tanhf(s);
    }
    __syncthreads();
    if (tid < 64) {
      int m = tid >> 2, oo = tid & 3;
      float s = bo2[oo];
#pragma unroll
      for (int k = 0; k < 32; ++k) s += gep[m * 32 + k] * Wo2[k * OQ + oo];
      out[(16 * c + m) * OQ + oo] = 1.f / (1.f + __expf(-s));
    }
  }
}

extern "C" void kernel_launch(void* const* d_in, const int* in_sizes, int n_in,
                              void* d_out, int out_size, void* d_ws, size_t ws_size,
                              hipStream_t stream) {
  (void)in_sizes; (void)n_in; (void)out_size; (void)ws_size;
  // zero counters + init flags every call (partials fully overwritten by protocol)
  hipMemsetAsync(d_ws, 0, 65536, stream);
  cde_kernel<<<dim3(256), dim3(THREADS), 0, stream>>>(
      (const float*)d_in[0],  (const float*)d_in[1],
      (const float*)d_in[2],  (const float*)d_in[3],
      (const float*)d_in[4],  (const float*)d_in[5],
      (const float*)d_in[6],  (const float*)d_in[7],
      (const float*)d_in[8],  (const float*)d_in[9],
      (const float*)d_in[10], (const float*)d_in[11],
      (const float*)d_in[12], (const float*)d_in[13],
      (const float*)d_in[14], (const float*)d_in[15],
      (float*)d_out, (unsigned char*)d_ws);
}

// Round 10
// 10133.491 us; speedup vs baseline: 1.0098x; 1.0098x over previous
//
#include <hip/hip_runtime.h>

// ============================================================================
// Neural CDE forward, MI355X. B=256, L=1024, I=16, H=128, W=512, O=4.
//
// 16 clusters x 16 blocks (256 = #CUs, co-resident). Cluster owns 16 batch
// rows. Weights resident in VGPRs (Wf1 replicated, Wf2 col-sliced, Wf3
// K-sliced). y state: full 16x128 fp32 replicated in every block.
//
// NUMERICS (new): all activations feeding MFMAs are hi/lo bf16 pairs
// (y, h1, h2*dx products; h2 kept fp32 in LDS) -> quantization noise
// 2^-9 -> ~2^-17. The ODE amplifies per-step rounding noise ~10^3-5x over
// 1023 steps (rounds 1-6 straddled the threshold at 2^-8..2^-6); this cuts
// the noise floor decisively. Weights stay single bf16 (systematic part,
// present in every passing round).
//
// EXCHANGE (1 RTT): each block scatters its fp32 partial dy (16x128) to its
// own slot (relaxed agent stores), drains, bumps a per-parity counter (RMW);
// consumers poll the counter, then all-read the 16 slots and reduce locally.
// 2-parity rotation; overwrite race-free via the bump<=read dependence chain.
// ============================================================================

constexpr int LQ = 1024, IQ = 16, HQ = 128, WQ = 512, OQ = 4;
constexpr int THREADS = 512;
constexpr size_t PCS   = 270336;
constexpr size_t PBASE = 65536;

typedef __attribute__((ext_vector_type(8))) short bf16x8;
typedef __attribute__((ext_vector_type(4))) float f32x4;
typedef unsigned int u32t;
typedef unsigned long long u64t;

#define MFMA16(a, b, c) __builtin_amdgcn_mfma_f32_16x16x32_bf16((a), (b), (c), 0, 0, 0)

__device__ __forceinline__ unsigned short f2bf(float f) {
  unsigned u = __builtin_bit_cast(unsigned, f);
  u += 0x7FFFu + ((u >> 16) & 1u);  // RNE
  return (unsigned short)(u >> 16);
}
__device__ __forceinline__ float bf2f(unsigned short h) {
  unsigned u = ((unsigned)h) << 16;
  return __builtin_bit_cast(float, u);
}
__device__ __forceinline__ float fast_tanh(float x) {
  float e = __expf(2.0f * x);
  return 1.0f - 2.0f / (e + 1.0f);
}
__device__ __forceinline__ u32t cvtpk(float lo, float hi) {
  u32t r;
  asm("v_cvt_pk_bf16_f32 %0, %1, %2" : "=v"(r) : "v"(lo), "v"(hi));
  return r;
}
// residual pair: given p0,p1 and their packed bf16 hi word, pack (p-hi) to bf16
__device__ __forceinline__ u32t lo_pair(float p0, float p1, u32t hpk) {
  float h0 = __builtin_bit_cast(float, hpk << 16);
  float h1 = __builtin_bit_cast(float, hpk & 0xffff0000u);
  return cvtpk(p0 - h0, p1 - h1);
}

// B-fragment: lane holds B[k0+8*(lane>>4)+j][n0+(lane&15)]
__device__ __forceinline__ bf16x8 load_bfrag(const float* W, int N, int k0, int n0, int lane) {
  const int col = n0 + (lane & 15);
  const int kb  = k0 + 8 * (lane >> 4);
  bf16x8 v;
#pragma unroll
  for (int j = 0; j < 8; ++j) v[j] = (short)f2bf(W[(kb + j) * N + col]);
  return v;
}

// ---- proven comm primitives: relaxed agent-scope atomics ----
__device__ __forceinline__ void st32a(u32t* p, u32t v) {
  __hip_atomic_store(p, v, __ATOMIC_RELAXED, __HIP_MEMORY_SCOPE_AGENT);
}
__device__ __forceinline__ u32t ld32a(const u32t* p) {
  return __hip_atomic_load(p, __ATOMIC_RELAXED, __HIP_MEMORY_SCOPE_AGENT);
}
__device__ __forceinline__ u64t ld64a(const u64t* p) {
  return __hip_atomic_load(p, __ATOMIC_RELAXED, __HIP_MEMORY_SCOPE_AGENT);
}
__device__ __forceinline__ void pollge(const u32t* p, u32t want) {
  while (ld32a(p) < want) __builtin_amdgcn_s_sleep(1);
  asm volatile("" ::: "memory");
}
__device__ __forceinline__ void drain_all() { __builtin_amdgcn_s_waitcnt(0); }

// ---- LDS pool layout (63.0 KB < 64 KB) ----
constexpr int OFF_YSH = 0;       // u16 y_sh[16][136]   4352            (epi: gep)
constexpr int OFF_YSL = 4352;    // u16 y_sl[16][136]   4352  -> 8704
constexpr int OFF_H1H = 8704;    // u16 h1h[16][520]   16640  -> 25344
constexpr int OFF_H1L = 25344;   // u16 h1l[16][520]   16640  -> 41984
constexpr int OFF_RED = 41984;   // f32 red[8][16][33] 16896  -> 58880  (epi: yf)
constexpr int OFF_B1  = 58880;   // f32 b1s[512]        2048  -> 60928
constexpr int OFF_B2  = 60928;   // f32 b2s[32]          128  -> 61056
constexpr int OFF_H2F = 61056;   // f32 h2f[16][33]     2112  -> 63168
constexpr int OFF_DX  = 63168;   // f32 dxs[16][20]     1280  -> 64448
constexpr int OFF_DT  = 64448;   // f32 dtl[16]           64  -> 64512
constexpr int POOLSZ  = 64512;
// h0f f32[16][512] (init only) overlays [0, 32768).

// ---- ws layout ----
// ws + c*256 + par*128          : u32 cnt[2]
// ws + 8192 + c*64              : u32 fy[16] (init broadcast flags)
// ws + PBASE + c*PCS            : f32 partial[par*16 + r][16*128]  (256 KB)
// ws + PBASE + c*PCS + 262144   : f32 y0b[16*128]                  (8 KB)

__global__ __launch_bounds__(THREADS, 1) void cde_kernel(
    const float* __restrict__ ts,  const float* __restrict__ x,
    const float* __restrict__ Wi1, const float* __restrict__ bi1,
    const float* __restrict__ Wi2, const float* __restrict__ bi2,
    const float* __restrict__ Wf1, const float* __restrict__ bfv1,
    const float* __restrict__ Wf2, const float* __restrict__ bfv2,
    const float* __restrict__ Wf3, const float* __restrict__ bfv3,
    const float* __restrict__ Wo1, const float* __restrict__ bo1,
    const float* __restrict__ Wo2, const float* __restrict__ bo2,
    float* __restrict__ out, unsigned char* __restrict__ ws) {
  const int tid  = threadIdx.x;
  const int wave = tid >> 6;
  const int lane = tid & 63;
  const int bid  = blockIdx.x;
  const int c    = bid >> 4;   // cluster: batch rows [16c, 16c+16)
  const int r    = bid & 15;   // rank: Wf2 cols [32r..), Wf3 rows [32r..)

  u32t* cnt = (u32t*)(ws + (size_t)c * 256);
  u32t* fy  = (u32t*)(ws + 8192 + (size_t)c * 64);
  float* part = (float*)(ws + PBASE + (size_t)c * PCS);
  float* y0b  = (float*)(ws + PBASE + (size_t)c * PCS + 262144);

  __shared__ __align__(16) unsigned char pool[POOLSZ];
  auto y_sh = (unsigned short(*)[136])(pool + OFF_YSH);
  auto y_sl = (unsigned short(*)[136])(pool + OFF_YSL);
  auto h1h  = (unsigned short(*)[520])(pool + OFF_H1H);
  auto h1l  = (unsigned short(*)[520])(pool + OFF_H1L);
  auto red  = (float(*)[16][33])(pool + OFF_RED);
  auto h2f  = (float(*)[33])(pool + OFF_H2F);
  auto h0f  = (float(*)[512])(pool);                 // init only
  float* b1s = (float*)(pool + OFF_B1);
  float* b2s = (float*)(pool + OFF_B2);
  float* dxs = (float*)(pool + OFF_DX);
  float* dtl = (float*)(pool + OFF_DT);

  // ---- resident weight fragments (single bf16, as all passing rounds) ----
  bf16x8 w1f[4][4];   // Wf1 replicated: wave w -> h1 cols [64w, 64w+64)
#pragma unroll
  for (int n = 0; n < 4; ++n)
#pragma unroll
    for (int k4 = 0; k4 < 4; ++k4)
      w1f[n][k4] = load_bfrag(Wf1, WQ, 32 * k4, 64 * wave + 16 * n, lane);
  const int w_nt = wave & 1, w_q = wave >> 1;
  bf16x8 w2f[4];      // Wf2 slice: n-half w_nt of cols [32r,32r+32), K-quarter w_q
#pragma unroll
  for (int kk = 0; kk < 4; ++kk)
    w2f[kk] = load_bfrag(Wf2, WQ, 32 * (4 * w_q + kk), 32 * r + 16 * w_nt, lane);
  bf16x8 w3f[16];     // B'[(k,j)][h] = Wf3[32r+k][16h+j]; wave -> h [16w,16w+16)
  {
    const int h = 16 * wave + (lane & 15);
#pragma unroll
    for (int kk = 0; kk < 16; ++kk) {
      bf16x8 v;
#pragma unroll
      for (int jj = 0; jj < 8; ++jj) {
        int Kp = 32 * kk + 8 * (lane >> 4) + jj;
        int k = Kp >> 4, j = Kp & 15;
        v[jj] = (short)f2bf(Wf3[(32 * r + k) * (HQ * IQ) + 16 * h + j]);
      }
      w3f[kk] = v;
    }
  }
  bf16x8 w3b;         // bias frag: B''[Kpp][h] = (Kpp<16) ? bfv3[16h+Kpp] : 0
  {
    const int h = 16 * wave + (lane & 15);
    bf16x8 v;
#pragma unroll
    for (int jj = 0; jj < 8; ++jj) {
      int Kpp = 8 * (lane >> 4) + jj;
      v[jj] = (Kpp < 16) ? (short)f2bf(bfv3[16 * h + Kpp]) : (short)0;
    }
    w3b = v;
  }

  b1s[tid] = bi1[tid];
  if (tid < 32) b2s[tid] = bfv2[32 * r + tid];

  // ---- init: h0 = tanh(x0 @ Wi1 + bi1); y0 slice = h0 @ Wi2 + bi2 ----
  {
    int row = tid >> 5, col0 = (tid & 31) * 16;
    const float* xr = x + ((16 * c + row) * LQ) * IQ;
    float xv[16];
#pragma unroll
    for (int j = 0; j < 16; ++j) xv[j] = xr[j];
    for (int cc = 0; cc < 16; ++cc) {
      int col = col0 + cc;
      float s = bi1[col];
#pragma unroll
      for (int j = 0; j < 16; ++j) s += xv[j] * Wi1[j * WQ + col];
      h0f[row][col] = tanhf(s);
    }
  }
  __syncthreads();
  if (tid < 128) {      // publish y0 slice (fp32) cols [8r, 8r+8)
    int m = tid >> 3, hl = tid & 7;
    float s = bi2[8 * r + hl];
#pragma unroll 8
    for (int k = 0; k < WQ; ++k) s += h0f[m][k] * Wi2[k * HQ + 8 * r + hl];
    st32a((u32t*)&y0b[m * HQ + 8 * r + hl], __builtin_bit_cast(u32t, s));
  }
  drain_all();
  __syncthreads();      // h0f reads done -> pool reusable
  if (tid == 0) st32a(fy + r, 1u);
  f32x4 y4;             // thread owns y[tid>>5][4*(tid&31) .. +4) fp32
  {
    pollge(fy + ((tid & 31) >> 1), 1u);
    u64t a = ld64a((const u64t*)(y0b + tid * 4));
    u64t b = ld64a((const u64t*)(y0b + tid * 4 + 2));
    y4[0] = __builtin_bit_cast(float, (u32t)a);
    y4[1] = __builtin_bit_cast(float, (u32t)(a >> 32));
    y4[2] = __builtin_bit_cast(float, (u32t)b);
    y4[3] = __builtin_bit_cast(float, (u32t)(b >> 32));
  }
  __syncthreads();

  const int g_row = tid >> 5, g_c4 = 4 * (tid & 31);
  const float* xrow = x + ((size_t)(16 * c + (tid >> 4))) * LQ * IQ + (tid & 15);
  const float* tsp  = ts + (size_t)(16 * c + tid) * LQ;

  // ======================= main scan: 1023 steps =======================
  for (int t = 0; t < LQ - 1; ++t) {
    const int par = t & 1;
    u32t* cntP = cnt + par * 32;
    float* slotW = part + (size_t)(par * 16 + r) * 2048;

    // issue dx/dt loads early
    float xa = 0.f, xb = 0.f, ta = 0.f, tb = 0.f;
    if (tid < 256) { const float* xp = xrow + t * IQ; xa = xp[0]; xb = xp[IQ]; }
    if (tid < 16)  { ta = tsp[t]; tb = tsp[t + 1]; }
    // pack y hi/lo (fp32 regs -> bf16 pair in LDS)
    {
      u32t h0 = cvtpk(y4[0], y4[1]), h1 = cvtpk(y4[2], y4[3]);
      u32t g0 = lo_pair(y4[0], y4[1], h0), g1 = lo_pair(y4[2], y4[3], h1);
      *(u64t*)&y_sh[g_row][g_c4] = ((u64t)h1 << 32) | (u64t)h0;
      *(u64t*)&y_sl[g_row][g_c4] = ((u64t)g1 << 32) | (u64t)g0;
    }
    __syncthreads();                                       // B1
    if (tid < 256) dxs[(tid >> 4) * 20 + (tid & 15)] = xb - xa;
    if (tid < 16)  dtl[tid] = tb - ta;
    // ---- P1: h1 = tanh((yh+yl) @ Wf1 + b1), wave w -> cols [64w, 64w+64) ----
    {
      bf16x8 afh[4], afl[4];
#pragma unroll
      for (int k4 = 0; k4 < 4; ++k4) {
        afh[k4] = *(const bf16x8*)&y_sh[lane & 15][32 * k4 + 8 * (lane >> 4)];
        afl[k4] = *(const bf16x8*)&y_sl[lane & 15][32 * k4 + 8 * (lane >> 4)];
      }
#pragma unroll
      for (int n = 0; n < 4; ++n) {
        f32x4 acc = {0.f, 0.f, 0.f, 0.f};
#pragma unroll
        for (int k4 = 0; k4 < 4; ++k4) acc = MFMA16(afh[k4], w1f[n][k4], acc);
#pragma unroll
        for (int k4 = 0; k4 < 4; ++k4) acc = MFMA16(afl[k4], w1f[n][k4], acc);
        const int col = 64 * wave + 16 * n + (lane & 15);
        const float bb = b1s[col];
#pragma unroll
        for (int i = 0; i < 4; ++i) {
          float hv = fast_tanh(acc[i] + bb);
          unsigned short hh = f2bf(hv);
          h1h[4 * (lane >> 4) + i][col] = hh;
          h1l[4 * (lane >> 4) + i][col] = f2bf(hv - bf2f(hh));
        }
      }
    }
    __syncthreads();                                       // B2
    // ---- P2: h2 slice partials, (h1h+h1l) @ Wf2 ----
    {
      f32x4 a0 = {0.f, 0.f, 0.f, 0.f}, a1 = {0.f, 0.f, 0.f, 0.f};
#pragma unroll
      for (int kk = 0; kk < 2; ++kk) {
        const int o0 = 32 * (4 * w_q + kk) + 8 * (lane >> 4);
        const int o1 = 32 * (4 * w_q + kk + 2) + 8 * (lane >> 4);
        a0 = MFMA16(*(const bf16x8*)&h1h[lane & 15][o0], w2f[kk], a0);
        a0 = MFMA16(*(const bf16x8*)&h1l[lane & 15][o0], w2f[kk], a0);
        a1 = MFMA16(*(const bf16x8*)&h1h[lane & 15][o1], w2f[kk + 2], a1);
        a1 = MFMA16(*(const bf16x8*)&h1l[lane & 15][o1], w2f[kk + 2], a1);
      }
#pragma unroll
      for (int i = 0; i < 4; ++i)
        red[wave][4 * (lane >> 4) + i][lane & 15] = a0[i] + a1[i];
    }
    __syncthreads();                                       // B3
    if (tid < 256) {   // reduce 4 K-partials + bias + tanh -> h2f (fp32, LDS)
      int row = tid >> 4, cp = tid & 15;
      int c0 = 2 * cp, c1 = c0 + 1, nt = cp >> 3, l0 = c0 & 15, l1 = c1 & 15;
      float v0 = b2s[c0], v1 = b2s[c1];
#pragma unroll
      for (int q = 0; q < 4; ++q) {
        v0 += red[(q << 1) | nt][row][l0];
        v1 += red[(q << 1) | nt][row][l1];
      }
      h2f[row][c0] = fast_tanh(v0);
      h2f[row][c1] = fast_tanh(v1);
    }
    __syncthreads();                                       // B4
    // ---- P3: partial dy via K'=(k,j)=512 MFMA, A' split hi/lo ----
    {
      const int b = lane & 15;
      const int ksel = (lane >> 5) & 1;      // which k of the pair this lane handles
      float dxsel[8];
#pragma unroll
      for (int jj = 0; jj < 8; ++jj)
        dxsel[jj] = dxs[b * 20 + ((lane & 16) ? 8 : 0) + jj];
      float hvv[16];
#pragma unroll
      for (int kk = 0; kk < 16; ++kk) hvv[kk] = h2f[b][2 * kk + ksel];
      f32x4 acc = {0.f, 0.f, 0.f, 0.f};
#pragma unroll
      for (int kk = 0; kk < 16; ++kk) {
        const float hv = hvv[kk];
        float p0 = hv * dxsel[0], p1 = hv * dxsel[1], p2 = hv * dxsel[2], p3 = hv * dxsel[3];
        float p4 = hv * dxsel[4], p5 = hv * dxsel[5], p6 = hv * dxsel[6], p7 = hv * dxsel[7];
        int4 hi, lo;
        hi.x = (int)cvtpk(p0, p1); lo.x = (int)lo_pair(p0, p1, (u32t)hi.x);
        hi.y = (int)cvtpk(p2, p3); lo.y = (int)lo_pair(p2, p3, (u32t)hi.y);
        hi.z = (int)cvtpk(p4, p5); lo.z = (int)lo_pair(p4, p5, (u32t)hi.z);
        hi.w = (int)cvtpk(p6, p7); lo.w = (int)lo_pair(p6, p7, (u32t)hi.w);
        acc = MFMA16(__builtin_bit_cast(bf16x8, hi), w3f[kk], acc);
        acc = MFMA16(__builtin_bit_cast(bf16x8, lo), w3f[kk], acc);
      }
      if (r == 0) {   // bias contribution (A'' = dx hi/lo), once per cluster
        int4 bh, bl;
        if (lane & 32) {
          bh.x = bh.y = bh.z = bh.w = 0; bl = bh;
        } else {
          bh.x = (int)cvtpk(dxsel[0], dxsel[1]); bl.x = (int)lo_pair(dxsel[0], dxsel[1], (u32t)bh.x);
          bh.y = (int)cvtpk(dxsel[2], dxsel[3]); bl.y = (int)lo_pair(dxsel[2], dxsel[3], (u32t)bh.y);
          bh.z = (int)cvtpk(dxsel[4], dxsel[5]); bl.z = (int)lo_pair(dxsel[4], dxsel[5], (u32t)bh.z);
          bh.w = (int)cvtpk(dxsel[6], dxsel[7]); bl.w = (int)lo_pair(dxsel[6], dxsel[7], (u32t)bh.w);
        }
        acc = MFMA16(__builtin_bit_cast(bf16x8, bh), w3b, acc);
        acc = MFMA16(__builtin_bit_cast(bf16x8, bl), w3b, acc);
      }
      // scatter fp32 partial to own slot
      const int hcol = 16 * wave + b;
#pragma unroll
      for (int i = 0; i < 4; ++i)
        st32a((u32t*)&slotW[(4 * (lane >> 4) + i) * 128 + hcol],
              __builtin_bit_cast(u32t, acc[i]));
    }
    drain_all();
    __syncthreads();                                       // B5
    if (tid == 0)
      __hip_atomic_fetch_add(cntP, 1u, __ATOMIC_RELAXED, __HIP_MEMORY_SCOPE_AGENT);
    pollge(cntP, 16u * (u32t)((t >> 1) + 1));
    // all-read the 16 partial slots (own 4 floats each), reduce, update y
    {
      float s0 = 0.f, s1 = 0.f, s2 = 0.f, s3 = 0.f;
#pragma unroll
      for (int i = 0; i < 16; ++i) {
        int rr = (r + i) & 15;   // stagger slot order across blocks
        const float* pb = part + (size_t)(par * 16 + rr) * 2048 + g_row * 128 + g_c4;
        u64t a = ld64a((const u64t*)pb);
        u64t b = ld64a((const u64t*)(pb + 2));
        s0 += __builtin_bit_cast(float, (u32t)a);
        s1 += __builtin_bit_cast(float, (u32t)(a >> 32));
        s2 += __builtin_bit_cast(float, (u32t)b);
        s3 += __builtin_bit_cast(float, (u32t)(b >> 32));
      }
      const float dtv = dtl[g_row];
      y4[0] += s0 * dtv; y4[1] += s1 * dtv; y4[2] += s2 * dtv; y4[3] += s3 * dtv;
    }
  }

  // ---- epilogue: y replicated fp32 in registers; block r==0 finishes ----
  if (r == 0) {
    float* yf = (float*)(pool + OFF_RED);   // f32 [16][128]
    {
#pragma unroll
      for (int i = 0; i < 4; ++i) yf[g_row * HQ + g_c4 + i] = y4[i];
    }
    __syncthreads();
    float* gep = (float*)(pool + OFF_YSH);  // f32 [16][32]
    {
      int m = tid >> 5, o = tid & 31;
      float s = bo1[o];
#pragma unroll 8
      for (int k = 0; k < HQ; ++k) s += yf[m * HQ + k] * Wo1[k * 32 + o];
      gep[m * 32 + o] = tanhf(s);
    }
    __syncthreads();
    if (tid < 64) {
      int m = tid >> 2, oo = tid & 3;
      float s = bo2[oo];
#pragma unroll
      for (int k = 0; k < 32; ++k) s += gep[m * 32 + k] * Wo2[k * OQ + oo];
      out[(16 * c + m) * OQ + oo] = 1.f / (1.f + __expf(-s));
    }
  }
}

extern "C" void kernel_launch(void* const* d_in, const int* in_sizes, int n_in,
                              void* d_out, int out_size, void* d_ws, size_t ws_size,
                              hipStream_t stream) {
  (void)in_sizes; (void)n_in; (void)out_size; (void)ws_size;
  // zero counters + init flags every call (partials fully overwritten by protocol)
  hipMemsetAsync(d_ws, 0, 65536, stream);
  cde_kernel<<<dim3(256), dim3(THREADS), 0, stream>>>(
      (const float*)d_in[0],  (const float*)d_in[1],
      (const float*)d_in[2],  (const float*)d_in[3],
      (const float*)d_in[4],  (const float*)d_in[5],
      (const float*)d_in[6],  (const float*)d_in[7],
      (const float*)d_in[8],  (const float*)d_in[9],
      (const float*)d_in[10], (const float*)d_in[11],
      (const float*)d_in[12], (const float*)d_in[13],
      (const float*)d_in[14], (const float*)d_in[15],
      (float*)d_out, (unsigned char*)d_ws);
}